// Round 5
// baseline (43.887 us; speedup 1.0000x reference)
//
#include <hip/hip_runtime.h>
#include <hip/hip_bf16.h>
#include <math.h>

#define NF 32
#define NH 8
#define NP 6

// ================= K1: per-feature mean + second-moment row =================
__global__ __launch_bounds__(256) void moments_kernel(
    const float* __restrict__ feat,
    float* __restrict__ mu,     // [NF]
    float* __restrict__ S,      // [NF][NF]
    int B)
{
    const int i = blockIdx.x;
    const int tid = threadIdx.x;
    float s = 0.f;
    float sj[NF];
#pragma unroll
    for (int j = 0; j < NF; j++) sj[j] = 0.f;

    for (int r = tid; r < B; r += 256) {
        const float* row = feat + (size_t)r * NF;
        const float4* row4 = (const float4*)row;
        float fi = row[i];
        s += fi;
#pragma unroll
        for (int jq = 0; jq < NF / 4; jq++) {
            float4 q = row4[jq];
            sj[4*jq+0] = fmaf(fi, q.x, sj[4*jq+0]);
            sj[4*jq+1] = fmaf(fi, q.y, sj[4*jq+1]);
            sj[4*jq+2] = fmaf(fi, q.z, sj[4*jq+2]);
            sj[4*jq+3] = fmaf(fi, q.w, sj[4*jq+3]);
        }
    }
#pragma unroll
    for (int d = 1; d < 64; d <<= 1) {
        s += __shfl_xor(s, d);
#pragma unroll
        for (int j = 0; j < NF; j++) sj[j] += __shfl_xor(sj[j], d);
    }
    __shared__ float red[4][NF + 1];
    const int wv = tid >> 6, lane = tid & 63;
    if (lane == 0) {
#pragma unroll
        for (int j = 0; j < NF; j++) red[wv][j] = sj[j];
        red[wv][NF] = s;
    }
    __syncthreads();
    if (tid < NF + 1) {
        float tot = red[0][tid] + red[1][tid] + red[2][tid] + red[3][tid];
        tot *= (1.0f / (float)B);
        if (tid < NF) S[(size_t)i * NF + tid] = tot;
        else mu[i] = tot;
    }
}

// ====== K2: analytic bn0+bn1 fold -> relu -> layer2 -> h2 + bn2 partials ======
__global__ __launch_bounds__(256) void mlp_kernel(
    const float* __restrict__ feat,
    const float* __restrict__ mu,
    const float* __restrict__ S,
    const float* __restrict__ bn0_g, const float* __restrict__ bn0_b,
    const float* __restrict__ W1, const float* __restrict__ b1,
    const float* __restrict__ bn1_g, const float* __restrict__ bn1_b,
    const float* __restrict__ W2, const float* __restrict__ b2,
    float* __restrict__ h2buf,
    float* __restrict__ part,   // [nb][2][NH]
    int B)
{
    __shared__ float ssc0[NF], ssh0[NF], smu[NF];
    __shared__ float w1p[NH][NF];
    __shared__ float Wf[NH][NF];
    __shared__ float bfold[NH];
    __shared__ float sW2[NH * NH], sb2[NH];
    __shared__ float vgrp[8];
    __shared__ float ssc1[NH];

    const int tid = threadIdx.x;
    if (tid < NF) {
        float m = mu[tid];
        smu[tid] = m;
        float var = S[(size_t)tid * NF + tid] - m * m;
        float sc = bn0_g[tid] * rsqrtf(var + 1e-5f);
        ssc0[tid] = sc;
        ssh0[tid] = bn0_b[tid] - m * sc;
    }
    if (tid >= 64 && tid < 64 + NH * NH) sW2[tid - 64] = W2[tid - 64];
    if (tid >= 128 && tid < 128 + NH) sb2[tid - 128] = b2[tid - 128];
    __syncthreads();
    {
        const int o = tid >> 5, i = tid & 31;
        w1p[o][i] = W1[o * NF + i] * ssc0[i];
    }
    __syncthreads();
    float vacc;
    {
        const int o = tid >> 5, i = tid & 31;
        float mi = smu[i];
        float acc = 0.f;
#pragma unroll
        for (int j = 0; j < NF; j++)
            acc = fmaf(S[(size_t)i * NF + j] - mi * smu[j], w1p[o][j], acc);
        vacc = acc * w1p[o][i];
    }
#pragma unroll
    for (int d = 1; d < 32; d <<= 1) vacc += __shfl_xor(vacc, d, 32);
    if ((tid & 31) == 0) vgrp[tid >> 5] = vacc;
    __syncthreads();
    if (tid < NH) {
        const int o = tid;
        float c1 = b1[o];
#pragma unroll
        for (int i = 0; i < NF; i++) c1 = fmaf(W1[o * NF + i], ssh0[i], c1);
        float m1 = c1;
#pragma unroll
        for (int i = 0; i < NF; i++) m1 = fmaf(w1p[o][i], smu[i], m1);
        float var1 = vgrp[o];
        float sc1 = bn1_g[o] * rsqrtf(var1 + 1e-5f);
        float sh1 = bn1_b[o] - m1 * sc1;
        ssc1[o] = sc1;
        bfold[o] = fmaf(sc1, c1, sh1);
    }
    __syncthreads();
    {
        const int o = tid >> 5, i = tid & 31;
        Wf[o][i] = ssc1[o] * w1p[o][i];
    }
    __syncthreads();

    const int r = blockIdx.x * 256 + tid;
    float h[NH];
    if (r < B) {
        float x[NF];
        const float4* row4 = (const float4*)(feat + (size_t)r * NF);
#pragma unroll
        for (int jq = 0; jq < NF / 4; jq++) {
            float4 q = row4[jq];
            x[4*jq+0] = q.x; x[4*jq+1] = q.y; x[4*jq+2] = q.z; x[4*jq+3] = q.w;
        }
        float x2[NH];
#pragma unroll
        for (int o = 0; o < NH; o++) {
            float z = bfold[o];
#pragma unroll
            for (int i = 0; i < NF; i++) z = fmaf(Wf[o][i], x[i], z);
            x2[o] = fmaxf(z, 0.f);
        }
#pragma unroll
        for (int o = 0; o < NH; o++) {
            float acc = sb2[o];
#pragma unroll
            for (int i = 0; i < NH; i++) acc = fmaf(sW2[o * NH + i], x2[i], acc);
            h[o] = acc;
            h2buf[(size_t)r * NH + o] = acc;
        }
    } else {
#pragma unroll
        for (int o = 0; o < NH; o++) h[o] = 0.f;
    }

    __shared__ float ls[NH][256];
    __shared__ float lq[NH][256];
#pragma unroll
    for (int o = 0; o < NH; o++) { ls[o][tid] = h[o]; lq[o][tid] = h[o] * h[o]; }
    __syncthreads();
    for (int st = 128; st > 0; st >>= 1) {
        if (tid < st) {
#pragma unroll
            for (int o = 0; o < NH; o++) {
                ls[o][tid] += ls[o][tid + st];
                lq[o][tid] += lq[o][tid + st];
            }
        }
        __syncthreads();
    }
    if (tid < NH) {
        part[(size_t)blockIdx.x * 2 * NH + tid] = ls[tid][0];
        part[(size_t)blockIdx.x * 2 * NH + NH + tid] = lq[tid][0];
    }
}

// ========= K3: bn2 finalize + params + single-pass scan, ONE BLOCK PER ROW =========
// 256 threads = 4 waves; lane chunk C = T/256 = 16. Wave-internal shuffle scan,
// then 4-entry LDS combine. Chunk composite [[P,0],[Q,P]]+(V1,V2); accumulator
// sensitivities A1,A2,A0 make the weighted sum affine in the incoming state.
__global__ __launch_bounds__(256) void scan_kernel(
    const float* __restrict__ X,
    const float* __restrict__ h2buf,
    const float* __restrict__ part,   // [nb][2][NH]
    const float* __restrict__ bn2_g, const float* __restrict__ bn2_b,
    const float* __restrict__ W3, const float* __restrict__ b3,
    const float* __restrict__ pn,
    const float* __restrict__ Fp,
    float* __restrict__ out, int B, int T, int nb)
{
    __shared__ float ssc2[NH], ssh2[NH];
    __shared__ float sW3[NP * NH], sb3[NP], spn[NP];
    __shared__ float sF;
    __shared__ float wcomp[4][4];     // per-wave composite P,Q,V1,V2
    __shared__ float rsum[4][2];      // per-wave contrib, wsum
    const int tid = threadIdx.x;
    if (tid < NH) {
        float s = 0.f, q = 0.f;
        for (int c = 0; c < nb; c++) {
            s += part[(size_t)c * 2 * NH + tid];
            q += part[(size_t)c * 2 * NH + NH + tid];
        }
        float inv_n = 1.0f / (float)B;
        float m = s * inv_n;
        float var = q * inv_n - m * m;
        float sc = bn2_g[tid] * rsqrtf(var + 1e-5f);
        ssc2[tid] = sc;
        ssh2[tid] = bn2_b[tid] - m * sc;
    }
    if (tid >= 64 && tid < 64 + NP * NH) sW3[tid - 64] = W3[tid - 64];
    if (tid >= 128 && tid < 128 + NP) sb3[tid - 128] = b3[tid - 128];
    if (tid >= 160 && tid < 160 + NP) spn[tid - 160] = pn[tid - 160];
    if (tid == 192) sF = Fp[0];
    __syncthreads();

    const int r = blockIdx.x;
    const int lane = tid & 63;
    const int wv = tid >> 6;

    // ---- params (thread-redundant, tiny; h2 row is L2-hot) ----
    float x3[NH];
#pragma unroll
    for (int i = 0; i < NH; i++) {
        float v = h2buf[(size_t)r * NH + i] * ssc2[i] + ssh2[i];
        x3[i] = fmaxf(v, 0.0f);
    }
    const float lo[NP] = {0.5f, 0.01f, 0.0f, 0.0f, 0.0f, 0.01f};
    const float hi[NP] = {5.0f, 0.5f, 2.0f, 2.0f, 1.0f, 0.5f};
    float p[NP];
#pragma unroll
    for (int j = 0; j < NP; j++) {
        float cr = sb3[j] + spn[j];
#pragma unroll
        for (int i = 0; i < NH; i++) cr = fmaf(sW3[j * NH + i], x3[i], cr);
        float sg = 1.0f / (1.0f + expf(-cr));
        p[j] = lo[j] + (hi[j] - lo[j]) * sg;
    }
    const float f_inf = p[1], df = p[0] - p[1];
    const float LOG2_0p7 = -0.5145731728297583f;
    const float LOG2_0p1 = -3.3219280948873623f;
    const float LOG2_10 = 3.3219280948873623f;
    float log2base = LOG2_0p7 + p[2] * LOG2_0p1;
    float invden = 0.1f * exp2f(LOG2_10 * p[3]);
    const float k = log2base * invden / (float)T;
    const float wsc = 1.0f / ((float)T * p[5]);
    const float wb = -p[4] / p[5];
    const float c = sqrtf(exp2f(1.0f / 3.0f) - 1.0f) * sF * (1.0f / 3.14159265358979323846f);
    const float c2 = 2.0f * c;

    // ---- per-lane chunk: composite + accumulator sensitivities ----
    const int C = T >> 8;             // 16
    const int t0 = tid * C;
    const float* Xr = X + (size_t)r * T;
    const float4* Xr4 = (const float4*)(Xr + t0);
    const float ek = exp2f(k);
    const float er = expf(-wsc);

    float e = exp2f(k * (float)t0);
    float E = expf(-(wsc * (float)t0 + wb));
    float xp = (tid == 0) ? 0.f : Xr[t0 - 1];

    float P = 1.f, Q = 0.f, V1 = 0.f, V2 = 0.f;
    float A1 = 0.f, A2 = 0.f, A0 = 0.f, wsum = 0.f;

    for (int j = 0; j < C / 4; j++) {
        float4 xq = Xr4[j];
        float xs[4] = {xq.x, xq.y, xq.z, xq.w};
#pragma unroll
        for (int m = 0; m < 4; m++) {
            const int t = t0 + j * 4 + m;
            const float x = xs[m];
            if (t == 0) {
                P = 0.f; Q = 0.f; V1 = x; V2 = x;
            } else {
                float ft = fmaf(df, e, f_inf);
                float inv = __builtin_amdgcn_rcpf(ft + c);
                float a = fmaf(-c2, inv, 1.0f);
                float b = fmaf(-c, inv, 1.0f);
                float u = b * (x + xp);
                float g = b * c2 * inv;    // b*(1-a)
                float Pn = -a * P;
                float Qn = fmaf(g, P, -a * Q);
                float V1n = fmaf(-a, V1, u);
                float V2n = fmaf(g, V1, fmaf(-a, V2, b * u));
                P = Pn; Q = Qn; V1 = V1n; V2 = V2n;
            }
            float w = __builtin_amdgcn_rcpf(1.0f + E);
            A1 = fmaf(w, Q, A1);
            A2 = fmaf(w, P, A2);
            A0 = fmaf(w, V2, A0);
            wsum += w;
            e *= ek;
            E *= er;
            xp = x;
        }
    }

    // ---- wave-internal inclusive scan of (P,Q,V1,V2) ----
#pragma unroll
    for (int d = 1; d < 64; d <<= 1) {
        float Po = __shfl_up(P, d);
        float Qo = __shfl_up(Q, d);
        float V1o = __shfl_up(V1, d);
        float V2o = __shfl_up(V2, d);
        if (lane >= d) {
            float Pn = P * Po;
            float Qn = fmaf(Q, Po, P * Qo);
            float V1n = fmaf(P, V1o, V1);
            float V2n = fmaf(Q, V1o, fmaf(P, V2o, V2));
            P = Pn; Q = Qn; V1 = V1n; V2 = V2n;
        }
    }

    // wave composite (lane 63 inclusive) -> LDS
    if (lane == 63) {
        wcomp[wv][0] = P; wcomp[wv][1] = Q; wcomp[wv][2] = V1; wcomp[wv][3] = V2;
    }

    // exclusive per-lane prefix
    float Pe = __shfl_up(P, 1);
    float Qe = __shfl_up(Q, 1);
    float V1e = __shfl_up(V1, 1);
    float V2e = __shfl_up(V2, 1);
    if (lane == 0) { Pe = 1.f; Qe = 0.f; V1e = 0.f; V2e = 0.f; }
    __syncthreads();

    // wave incoming state: compose preceding wave composites onto (0,0)
    float y1s = 0.f, y2s = 0.f;
    for (int i = 0; i < wv; i++) {
        float Pi = wcomp[i][0], Qi = wcomp[i][1], V1i = wcomp[i][2], V2i = wcomp[i][3];
        float y1n = fmaf(Pi, y1s, V1i);
        float y2n = fmaf(Qi, y1s, fmaf(Pi, y2s, V2i));
        y1s = y1n; y2s = y2n;
    }

    // lane incoming state
    float y1in = fmaf(Pe, y1s, V1e);
    float y2in = fmaf(Qe, y1s, fmaf(Pe, y2s, V2e));

    float contrib = fmaf(A1, y1in, fmaf(A2, y2in, A0));
#pragma unroll
    for (int d = 1; d < 64; d <<= 1) {
        contrib += __shfl_xor(contrib, d);
        wsum += __shfl_xor(wsum, d);
    }
    if (lane == 0) { rsum[wv][0] = contrib; rsum[wv][1] = wsum; }
    __syncthreads();
    if (tid == 0) {
        float ct = rsum[0][0] + rsum[1][0] + rsum[2][0] + rsum[3][0];
        float wt = rsum[0][1] + rsum[1][1] + rsum[2][1] + rsum[3][1];
        out[r] = ct / wt;
    }
}

extern "C" void kernel_launch(void* const* d_in, const int* in_sizes, int n_in,
                              void* d_out, int out_size, void* d_ws, size_t ws_size,
                              hipStream_t stream) {
    const float* X = (const float*)d_in[0];
    const float* features = (const float*)d_in[1];
    const float* Fp = (const float*)d_in[2];
    const float* bn0_g = (const float*)d_in[3];
    const float* bn0_b = (const float*)d_in[4];
    const float* W1 = (const float*)d_in[5];
    const float* b1 = (const float*)d_in[6];
    const float* bn1_g = (const float*)d_in[7];
    const float* bn1_b = (const float*)d_in[8];
    const float* W2 = (const float*)d_in[9];
    const float* b2 = (const float*)d_in[10];
    const float* bn2_g = (const float*)d_in[11];
    const float* bn2_b = (const float*)d_in[12];
    const float* W3 = (const float*)d_in[13];
    const float* b3 = (const float*)d_in[14];
    const float* pn = (const float*)d_in[15];
    float* out = (float*)d_out;

    const int B = in_sizes[1] / NF;      // 2048
    const int T = in_sizes[0] / B;       // 4096
    const int nb = (B + 255) / 256;      // 8

    float* ws = (float*)d_ws;
    float* mu = ws;                           // 32
    float* S = ws + NF;                       // 32*32
    float* part = S + NF * NF;                // nb*16
    float* h2buf = part + (size_t)nb * 16;    // B*8

    moments_kernel<<<NF, 256, 0, stream>>>(features, mu, S, B);
    mlp_kernel<<<nb, 256, 0, stream>>>(features, mu, S, bn0_g, bn0_b, W1, b1,
                                       bn1_g, bn1_b, W2, b2, h2buf, part, B);
    scan_kernel<<<B, 256, 0, stream>>>(X, h2buf, part, bn2_g, bn2_b,
                                       W3, b3, pn, Fp, out, B, T, nb);
}